// Round 1
// baseline (17689.038 us; speedup 1.0000x reference)
//
#include <hip/hip_runtime.h>
#include <hip/hip_bf16.h>

#define B_   128
#define T_   512
#define D_   512
#define U_   1024
#define O_   512
#define K_   1536      // D + U
#define G4U_ 4096
#define NBLK 256

typedef __attribute__((ext_vector_type(8))) short short8;
typedef __attribute__((ext_vector_type(4))) float f32x4;

// Static device scratch (harness d_ws size unknown; statics are safe and are
// fully rewritten every call before use).
__device__ __align__(16) unsigned short g_xbf[(size_t)B_ * T_ * D_];   // x as bf16 [b][t][d]
__device__ __align__(16) unsigned short g_Wt[(size_t)G4U_ * K_];       // combined W, transposed+gate-grouped [cg][k]
__device__ __align__(16) unsigned short g_Wdt[(size_t)O_ * U_];        // Wd transposed [o][u]
__device__ __align__(16) unsigned short g_h[2][(size_t)B_ * U_];       // double-buffered h (bf16)
__device__ unsigned int g_bar;                                          // barrier counter (monotonic per call)

__device__ __forceinline__ unsigned short f2b(float f) {
  unsigned u = __float_as_uint(f);
  u += 0x7fffu + ((u >> 16) & 1u);   // RNE
  return (unsigned short)(u >> 16);
}

__global__ void prep_kernel(const float* __restrict__ x, const float* __restrict__ h0,
                            const float* __restrict__ kern, const float* __restrict__ rkern,
                            const float* __restrict__ Wd) {
  size_t tid = (size_t)blockIdx.x * blockDim.x + threadIdx.x;
  size_t np  = (size_t)gridDim.x * blockDim.x;
  if (tid == 0) g_bar = 0u;

  // x -> bf16, vectorized by 8
  const size_t nx8 = (size_t)B_ * T_ * D_ / 8;
  const float4* xv = (const float4*)x;
  for (size_t i = tid; i < nx8; i += np) {
    float4 v0 = xv[2 * i], v1 = xv[2 * i + 1];
    unsigned short tmp[8];
    tmp[0] = f2b(v0.x); tmp[1] = f2b(v0.y); tmp[2] = f2b(v0.z); tmp[3] = f2b(v0.w);
    tmp[4] = f2b(v1.x); tmp[5] = f2b(v1.y); tmp[6] = f2b(v1.z); tmp[7] = f2b(v1.w);
    *(int4*)&g_xbf[i * 8] = *(const int4*)tmp;
  }

  // Combined weights, transposed so k is contiguous, columns gate-grouped:
  // stored row cg = cgrp*64 + gate*16 + j  ->  natural col n = gate*1024 + cgrp*16 + j
  // Wt[cg][k] = (k<512 ? kernel[k][n] : rec_kernel[k-512][n])
  const size_t nw = (size_t)G4U_ * (K_ / 8);
  for (size_t i = tid; i < nw; i += np) {
    size_t cg = i / (K_ / 8);
    int kb = (int)(i % (K_ / 8)) * 8;
    int c = (int)(cg >> 6), g = (int)((cg >> 4) & 3), j = (int)(cg & 15);
    int n = g * 1024 + (c << 4) + j;
    unsigned short tmp[8];
#pragma unroll
    for (int q = 0; q < 8; ++q) {
      int k = kb + q;
      float v = (k < 512) ? kern[(size_t)k * G4U_ + n] : rkern[(size_t)(k - 512) * G4U_ + n];
      tmp[q] = f2b(v);
    }
    *(int4*)&g_Wt[cg * K_ + kb] = *(const int4*)tmp;
  }

  // Wd transposed: Wdt[o][u] = Wd[u][o]
  const size_t nd = (size_t)O_ * (U_ / 8);
  for (size_t i = tid; i < nd; i += np) {
    int o  = (int)(i >> 7);
    int ub = (int)(i & 127) * 8;
    unsigned short tmp[8];
#pragma unroll
    for (int q = 0; q < 8; ++q) tmp[q] = f2b(Wd[(size_t)(ub + q) * O_ + o]);
    *(int4*)&g_Wdt[(size_t)o * U_ + ub] = *(const int4*)tmp;
  }

  // h0 -> bf16 into buffer 0
  const size_t nh = (size_t)B_ * U_;
  for (size_t i = tid; i < nh; i += np) g_h[0][i] = f2b(h0[i]);
}

// Persistent recurrence kernel: 256 blocks x 512 threads, one grid barrier per step.
// Block b: m-group = b>>6 (32 rows), u-group cgrp = b&63 (16 u cols, all 4 gates).
// XCD = b%8 = cgrp%8 -> each XCD's W slice (1.57 MB) stays L2-resident.
__global__ __launch_bounds__(512) void lstm_kernel(const float* __restrict__ c0,
                                                   const float* __restrict__ bias,
                                                   const float* __restrict__ bd,
                                                   float* __restrict__ out) {
  const int b    = blockIdx.x;
  const int tid  = threadIdx.x;
  const int wave = tid >> 6;
  const int lane = tid & 63;
  const int m0   = (b >> 6) * 32;
  const int cgrp = b & 63;
  const int u0   = cgrp * 16;
  const int gate = wave & 3;   // wave's gate
  const int kh   = wave >> 2;  // wave's k-parity (K split 2-way, interleaved by 32)

  __shared__ __align__(16) unsigned short Ast[32 * 264];  // A stage: 32 rows x 256 k (+8 pad)
  __shared__ float zl[4][2][32][16];                       // [gate][kh][row][u] partial z
  __shared__ float po[8][16][16];                          // out-proj partials per wave

  // persistent cell state: one element per thread
  const int crow = tid >> 4;   // 0..31
  const int cu   = tid & 15;   // 0..15
  float c_val = c0[(size_t)(m0 + crow) * U_ + u0 + cu];
  float bias_g[4];
#pragma unroll
  for (int g = 0; g < 4; ++g) bias_g[g] = bias[g * 1024 + u0 + cu];

  // out-projection tile: rows om0..+16, cols oo0..+16
  const int om0 = (b >> 5) * 16;
  const int oo0 = (b & 31) * 16;
  const float bd_val = bd[oo0 + (tid & 15)];

  // MFMA fragment lane mapping (16x16x32): line = lane&15, k-subgroup = (lane>>4)*8
  const int fr = lane & 15;
  const int fk = (lane >> 4) * 8;

  const unsigned short* wrow = &g_Wt[(size_t)(cgrp * 64 + gate * 16 + fr) * K_];

  int cur = 0;
  for (int t = 0; t < T_; ++t) {
    // ---------------- z = [x_t | h] @ W  (K=1536) ----------------
    f32x4 acc0 = {0.f, 0.f, 0.f, 0.f};   // rows 0..15 of m-group
    f32x4 acc1 = {0.f, 0.f, 0.f, 0.f};   // rows 16..31
    const unsigned short* hcur = g_h[cur];

    for (int ch = 0; ch < 6; ++ch) {
      const int k0c = ch * 256;
      {  // stage A chunk (32 rows x 256 k) into LDS, 32 B per thread
        const int r  = tid >> 4;
        const int kk = (tid & 15) * 16;
        const unsigned short* src = (k0c < 512)
            ? &g_xbf[((size_t)(m0 + r) * T_ + t) * D_ + (k0c + kk)]
            : &hcur[(size_t)(m0 + r) * U_ + (k0c - 512 + kk)];
        const int4* s4 = (const int4*)src;
        int4 v0 = s4[0], v1 = s4[1];
        int4* d4 = (int4*)&Ast[r * 264 + kk];
        d4[0] = v0; d4[1] = v1;
      }
      __syncthreads();
#pragma unroll
      for (int s = 0; s < 4; ++s) {
        const int ks = (2 * s + kh) * 32;
        short8 a0 = *(const short8*)&Ast[fr * 264 + ks + fk];
        short8 a1 = *(const short8*)&Ast[(16 + fr) * 264 + ks + fk];
        short8 bq = *(const short8*)&wrow[k0c + ks + fk];
        acc0 = __builtin_amdgcn_mfma_f32_16x16x32_bf16(a0, bq, acc0, 0, 0, 0);
        acc1 = __builtin_amdgcn_mfma_f32_16x16x32_bf16(a1, bq, acc1, 0, 0, 0);
      }
      __syncthreads();
    }

    // C-layout: col = lane&15, row = (lane>>4)*4 + r
#pragma unroll
    for (int r = 0; r < 4; ++r) {
      const int row = (lane >> 4) * 4 + r;
      zl[gate][kh][row][fr]      = acc0[r];
      zl[gate][kh][16 + row][fr] = acc1[r];
    }
    __syncthreads();

    // ---------------- gates + state update (fp32) ----------------
    {
      float zi = zl[0][0][crow][cu] + zl[0][1][crow][cu] + bias_g[0];
      float zf = zl[1][0][crow][cu] + zl[1][1][crow][cu] + bias_g[1];
      float zg = zl[2][0][crow][cu] + zl[2][1][crow][cu] + bias_g[2];
      float zo = zl[3][0][crow][cu] + zl[3][1][crow][cu] + bias_g[3];
      float ig = 1.f / (1.f + __expf(-zi));
      float fg = 1.f / (1.f + __expf(-zf));
      float og = 1.f / (1.f + __expf(-zo));
      float gg = tanhf(zg);
      c_val = fg * c_val + ig * gg;
      float hv = og * tanhf(c_val);
      g_h[cur ^ 1][(size_t)(m0 + crow) * U_ + u0 + cu] = f2b(hv);
    }
    __syncthreads();

    // ---------------- grid barrier (monotonic counter) ----------------
    if (tid == 0) {
      __threadfence();
      __hip_atomic_fetch_add(&g_bar, 1u, __ATOMIC_RELEASE, __HIP_MEMORY_SCOPE_AGENT);
      const unsigned tgt = (unsigned)NBLK * (unsigned)(t + 1);
      while (__hip_atomic_load(&g_bar, __ATOMIC_ACQUIRE, __HIP_MEMORY_SCOPE_AGENT) < tgt)
        __builtin_amdgcn_s_sleep(2);
      __threadfence();
    }
    __syncthreads();

    // ---------------- out_t = h_t @ Wd + bd (16x16 tile, K split over 8 waves) ----------------
    {
      const unsigned short* hnew = g_h[cur ^ 1];
      f32x4 oacc = {0.f, 0.f, 0.f, 0.f};
      const int kbase = wave * 128;
#pragma unroll
      for (int s = 0; s < 4; ++s) {
        const int k = kbase + s * 32;
        short8 a  = *(const short8*)&hnew[(size_t)(om0 + fr) * U_ + k + fk];
        short8 bq = *(const short8*)&g_Wdt[(size_t)(oo0 + fr) * U_ + k + fk];
        oacc = __builtin_amdgcn_mfma_f32_16x16x32_bf16(a, bq, oacc, 0, 0, 0);
      }
#pragma unroll
      for (int r = 0; r < 4; ++r) po[wave][(lane >> 4) * 4 + r][fr] = oacc[r];
      __syncthreads();
      if (tid < 256) {
        const int row = tid >> 4, oc = tid & 15;
        float sacc = bd_val;
#pragma unroll
        for (int w2 = 0; w2 < 8; ++w2) sacc += po[w2][row][oc];
        out[((size_t)(om0 + row) * T_ + t) * O_ + oo0 + oc] = sacc;
      }
      __syncthreads();
    }
    cur ^= 1;
  }
}

extern "C" void kernel_launch(void* const* d_in, const int* in_sizes, int n_in,
                              void* d_out, int out_size, void* d_ws, size_t ws_size,
                              hipStream_t stream) {
  const float* x    = (const float*)d_in[0];
  const float* h0   = (const float*)d_in[1];
  const float* c0   = (const float*)d_in[2];
  const float* kern = (const float*)d_in[3];
  const float* rk   = (const float*)d_in[4];
  const float* bias = (const float*)d_in[5];
  const float* Wd   = (const float*)d_in[6];
  const float* bd   = (const float*)d_in[7];
  float* out = (float*)d_out;
  (void)in_sizes; (void)n_in; (void)d_ws; (void)ws_size; (void)out_size;

  prep_kernel<<<dim3(1024), dim3(256), 0, stream>>>(x, h0, kern, rk, Wd);
  lstm_kernel<<<dim3(NBLK), dim3(512), 0, stream>>>(c0, bias, bd, out);
}